// Round 1
// baseline (25.674 us; speedup 1.0000x reference)
//
#include <hip/hip_runtime.h>

// GMP kernel: y[b,s] = sum_{l=0}^{L-1} C_l(b,s) * x[b,s-l], masked for s < D.
// C_l = sum_{k=0}^{K-1} a[k, L-1-l] |x[s-l]|^k
//     + sum_{m=0}^{M-1} sum_{k=1}^{K} b[k-1,l,m] |x[s-l-1-m]|^k
// K=4, L=10, M=10, D=20. All fp32. Input c is unused by the reference.

constexpr int Kp = 4;
constexpr int Lp = 10;
constexpr int Mp = 10;
constexpr int Dp = Lp + Mp;   // 20
constexpr int BLK = 256;
constexpr int S_FIXED = 16384;

__global__ __launch_bounds__(BLK) void gmp_kernel(
    const float* __restrict__ x,   // (B, S, 2)
    const float* __restrict__ a,   // (K, L)
    const float* __restrict__ b,   // (K, L, M)
    float* __restrict__ out,       // (B, S, 2)
    int S)
{
    __shared__ float2 sx[BLK + Dp];        // halo tile: sx[i] = x[s0 - (Dp-1) + i]
    __shared__ float  sa[Lp][4];           // sa[l][k] = a[k, Lp-1-l]
    __shared__ float  sb[Lp * Mp][4];      // sb[l*Mp+m][k] = b[k, l, m]

    const int t = threadIdx.x;
    const int blocksPerRow = S / BLK;
    const int brow = blockIdx.x / blocksPerRow;
    const int s0   = (blockIdx.x % blocksPerRow) * BLK;

    // --- stage coefficients (transposed, k contiguous for float4 reads) ---
    if (t < Lp) {
        #pragma unroll
        for (int k = 0; k < Kp; ++k) sa[t][k] = a[k * Lp + (Lp - 1 - t)];
    }
    if (t >= 64 && t < 64 + Lp * Mp) {     // threads 64..163 stage b (spread work)
        const int lm = t - 64;             // lm = l*Mp + m; b[k][l][m] = b[k*100 + lm]
        #pragma unroll
        for (int k = 0; k < Kp; ++k) sb[lm][k] = b[k * Lp * Mp + lm];
    }

    // --- stage x tile with left halo of Dp-1 samples ---
    const float2* xrow = reinterpret_cast<const float2*>(x) + (size_t)brow * S;
    for (int i = t; i < BLK + Dp - 1; i += BLK) {
        const int s = s0 - (Dp - 1) + i;
        sx[i] = (s >= 0) ? xrow[s] : make_float2(0.f, 0.f);
    }
    __syncthreads();

    const int s = s0 + t;
    float2 o = make_float2(0.f, 0.f);
    if (s >= Dp) {
        // local index of sample (s - d) in sx is  t + (Dp-1) - d
        float q1[Dp], q2[Dp], q3[Dp], q4[Dp];
        float re[Lp], im[Lp];
        #pragma unroll
        for (int d = 0; d < Dp; ++d) {
            const float2 v = sx[t + (Dp - 1) - d];
            const float m2 = v.x * v.x + v.y * v.y;
            const float r  = sqrtf(m2);
            q1[d] = r;
            q2[d] = m2;
            q3[d] = m2 * r;
            q4[d] = m2 * m2;
            if (d < Lp) { re[d] = v.x; im[d] = v.y; }
        }
        float yr = 0.f, yi = 0.f;
        #pragma unroll
        for (int l = 0; l < Lp; ++l) {
            const float4 ac = *reinterpret_cast<const float4*>(sa[l]);
            float C = ac.x + ac.y * q1[l] + ac.z * q2[l] + ac.w * q3[l];
            #pragma unroll
            for (int m = 0; m < Mp; ++m) {
                const int d = l + 1 + m;
                const float4 bc = *reinterpret_cast<const float4*>(sb[l * Mp + m]);
                C += bc.x * q1[d] + bc.y * q2[d] + bc.z * q3[d] + bc.w * q4[d];
            }
            yr += C * re[l];
            yi += C * im[l];
        }
        o.x = yr;
        o.y = yi;
    }
    reinterpret_cast<float2*>(out)[(size_t)brow * S + s] = o;
}

extern "C" void kernel_launch(void* const* d_in, const int* in_sizes, int n_in,
                              void* d_out, int out_size, void* d_ws, size_t ws_size,
                              hipStream_t stream) {
    const float* x = (const float*)d_in[0];
    const float* a = (const float*)d_in[1];
    const float* b = (const float*)d_in[2];
    // d_in[3] (c) is unused by the reference.
    float* out = (float*)d_out;

    const int S = S_FIXED;
    const int B = in_sizes[0] / (2 * S);
    const int nblocks = B * (S / BLK);

    gmp_kernel<<<dim3(nblocks), dim3(BLK), 0, stream>>>(x, a, b, out, S);
}